// Round 4
// baseline (739.783 us; speedup 1.0000x reference)
//
#include <hip/hip_runtime.h>

#define BATCH 8
#define L 2048
#define D 1024

// ws layout:
//  [ at : B*D*L bf16 ][ bt : B*D*L bf16 ]            (transposed single-bf16, W operands)
//  [ ah ][ al ][ bh ][ bl ] : B*L*D bf16 each        (hi/lo split planes, row-major [i][d])
//  [ slots... ] each slot (float units):
//    e (L*L fp32) | Pb (L*L bf16, unnorm) | PaT (L*L bf16, unnorm) | stats (28*L f32)
#define PB_OFF  (L * L)
#define PAT_OFF (L * L + (L * L) / 2)
#define STAT    (2 * L * L)
// stat sub-offsets (floats, relative to slot+STAT)
#define ROWINV  0            // L       1/rowsum (from k_rowsoft)
#define CMAXP   (L)          // 16*L    partial col-max per 128-row i-block (from gemm epilogue)
#define CMAX    (17 * L)     // L       final col-max
#define CSUMP   (18 * L)     // 8*L     partial col-sums per 256-row chunk
#define CINV    (26 * L)     // L       1/colsum
#define SLOT_F  (2 * L * L + 28 * L)

typedef __attribute__((ext_vector_type(8))) short bf16x8;
typedef __attribute__((ext_vector_type(4))) float f32x4;

static __device__ inline unsigned short f2bf(float x) {
  union { float f; unsigned u; } v; v.f = x;
  unsigned r = v.u + 0x7fff + ((v.u >> 16) & 1);   // RNE (inputs finite)
  return (unsigned short)(r >> 16);
}
static __device__ inline float bf2f(unsigned short h) {
  union { unsigned u; float f; } v; v.u = ((unsigned)h) << 16; return v.f;
}
static __device__ inline unsigned pack2(float x, float y) {
  return (unsigned)f2bf(x) | ((unsigned)f2bf(y) << 16);
}
static __device__ inline void split2(float x, float y, unsigned &hi, unsigned &lo) {
  unsigned short hx = f2bf(x), hy = f2bf(y);
  float rx = x - bf2f(hx), ry = y - bf2f(hy);
  hi = (unsigned)hx | ((unsigned)hy << 16);
  lo = (unsigned)f2bf(rx) | ((unsigned)f2bf(ry) << 16);
}

#define GLL16(gp, lp) __builtin_amdgcn_global_load_lds(                        \
    (const __attribute__((address_space(1))) void*)(gp),                       \
    (__attribute__((address_space(3))) void*)(lp), 16, 0, 0)

// Stage one 128x32 bf16 tile (8 KiB) global->LDS, linear layout [128][32].
static __device__ inline void stage2(const unsigned short* __restrict__ g,
                                     size_t o0, size_t o1,
                                     unsigned short* l, int wb) {
  GLL16(g + o0, l + wb);
  GLL16(g + o1, l + wb + 2048);
}

// ---------------------------------------------------------------------------
// k_prep: at[b][d][i] = bf16(a[b][i][d]) (and bt from b) for the PV W-operand;
// plus hi/lo split planes ah/al (bh/bl) row-major [i][d].
// ---------------------------------------------------------------------------
__global__ __launch_bounds__(256) void k_prep(const float* __restrict__ A,
                                              const float* __restrict__ Bm,
                                              unsigned short* __restrict__ at,
                                              unsigned short* __restrict__ bt,
                                              unsigned short* __restrict__ ah,
                                              unsigned short* __restrict__ al,
                                              unsigned short* __restrict__ bh,
                                              unsigned short* __restrict__ bl) {
  const int z = blockIdx.z, batch = z & 7;
  const bool isA = z < 8;
  const float* src = (isA ? A : Bm) + (size_t)batch * L * D;
  unsigned short* dst = (isA ? at : bt) + (size_t)batch * D * L;
  unsigned short* ph = (isA ? ah : bh) + (size_t)batch * L * D;
  unsigned short* pl = (isA ? al : bl) + (size_t)batch * L * D;
  const int i0 = blockIdx.x * 64, d0 = blockIdx.y * 64;
  __shared__ float sT[64][65];
  const int tid = threadIdx.x;
#pragma unroll
  for (int it = 0; it < 4; ++it) {
    int idx = tid + it * 256;
    int row = idx >> 4, c4 = (idx & 15) * 4;
    float4 v = *(const float4*)(src + (size_t)(i0 + row) * D + d0 + c4);
    unsigned h0, l0, h1, l1;
    split2(v.x, v.y, h0, l0); split2(v.z, v.w, h1, l1);
    size_t po = (size_t)(i0 + row) * D + d0 + c4;
    *(uint2*)&ph[po] = make_uint2(h0, h1);
    *(uint2*)&pl[po] = make_uint2(l0, l1);
    sT[row][c4 + 0] = v.x; sT[row][c4 + 1] = v.y;
    sT[row][c4 + 2] = v.z; sT[row][c4 + 3] = v.w;
  }
  __syncthreads();
#pragma unroll
  for (int it = 0; it < 4; ++it) {
    int idx = tid + it * 256;
    int orow = idx >> 4, c4 = (idx & 15) * 4;
    uint2 o = make_uint2(pack2(sT[c4 + 0][orow], sT[c4 + 1][orow]),
                         pack2(sT[c4 + 2][orow], sT[c4 + 3][orow]));
    *(uint2*)&dst[(size_t)(d0 + orow) * L + i0 + c4] = o;
  }
}

// ---------------------------------------------------------------------------
// Kernel 1: e = a @ b^T (split-bf16: hh + hl + lh) from pre-split planes.
// 128x128 tile, BK=32, global_load_lds staging. Epilogue additionally emits
// per-128-row-block col-max partials (free col-softmax stats from live accs).
// pcm aliases sAh (dead after K-loop) to keep LDS at exactly 32 KiB ->
// 5 blocks/CU (R3's separate pcm[128] pushed LDS to 33280 -> 4 blocks/CU,
// occupancy 29.6->21.5%, +38 us).
// ---------------------------------------------------------------------------
__global__ __launch_bounds__(256) void k_gemm_e(const unsigned short* __restrict__ ah,
                                                const unsigned short* __restrict__ al,
                                                const unsigned short* __restrict__ bh,
                                                const unsigned short* __restrict__ bl,
                                                float* __restrict__ ws, int b0) {
  const int bz = blockIdx.z, batch = b0 + bz;
  const size_t po = (size_t)batch * L * D;
  float* e = ws + (size_t)bz * SLOT_F;
  const int i0 = blockIdx.x * 128, j0 = blockIdx.y * 128;
  __shared__ unsigned short sAh[128 * 32], sAl[128 * 32];
  __shared__ unsigned short sBh[128 * 32], sBl[128 * 32];
  float* pcm = (float*)sAh;              // aliased: sAh dead after K-loop
  const int tid = threadIdx.x, lane = tid & 63, wave = tid >> 6;
  const int wm = (wave & 1) * 64, wn = (wave >> 1) * 64;
  const int q = lane >> 4, lr = lane & 15;
  const int soff = wave * 1024 + lane * 16;
  const int srow = soff >> 6, scol = (soff & 63) >> 1;
  const int wb = wave * 512;
  const unsigned short* gAh = ah + po; const unsigned short* gAl = al + po;
  const unsigned short* gBh = bh + po; const unsigned short* gBl = bl + po;
  const size_t ga0 = (size_t)(i0 + srow) * D + scol, ga1 = ga0 + (size_t)64 * D;
  const size_t gb0 = (size_t)(j0 + srow) * D + scol, gb1 = gb0 + (size_t)64 * D;
  f32x4 acc[4][4] = {};
  for (int k0 = 0; k0 < D; k0 += 32) {
    __syncthreads();
    stage2(gAh, ga0 + k0, ga1 + k0, sAh, wb);
    stage2(gAl, ga0 + k0, ga1 + k0, sAl, wb);
    stage2(gBh, gb0 + k0, gb1 + k0, sBh, wb);
    stage2(gBl, gb0 + k0, gb1 + k0, sBl, wb);
    __syncthreads();
    bf16x8 fah[4], fbh[4], fx[4];
#pragma unroll
    for (int t = 0; t < 4; ++t) {
      fah[t] = *(const bf16x8*)&sAh[(wm + t * 16 + lr) * 32 + q * 8];
      fbh[t] = *(const bf16x8*)&sBh[(wn + t * 16 + lr) * 32 + q * 8];
    }
#pragma unroll
    for (int mi = 0; mi < 4; ++mi)
#pragma unroll
      for (int ni = 0; ni < 4; ++ni)
        acc[mi][ni] = __builtin_amdgcn_mfma_f32_16x16x32_bf16(fah[mi], fbh[ni], acc[mi][ni], 0, 0, 0);
#pragma unroll
    for (int t = 0; t < 4; ++t)
      fx[t] = *(const bf16x8*)&sBl[(wn + t * 16 + lr) * 32 + q * 8];
#pragma unroll
    for (int mi = 0; mi < 4; ++mi)
#pragma unroll
      for (int ni = 0; ni < 4; ++ni)
        acc[mi][ni] = __builtin_amdgcn_mfma_f32_16x16x32_bf16(fah[mi], fx[ni], acc[mi][ni], 0, 0, 0);
#pragma unroll
    for (int t = 0; t < 4; ++t)
      fx[t] = *(const bf16x8*)&sAl[(wm + t * 16 + lr) * 32 + q * 8];
#pragma unroll
    for (int mi = 0; mi < 4; ++mi)
#pragma unroll
      for (int ni = 0; ni < 4; ++ni)
        acc[mi][ni] = __builtin_amdgcn_mfma_f32_16x16x32_bf16(fx[mi], fbh[ni], acc[mi][ni], 0, 0, 0);
  }
#pragma unroll
  for (int mi = 0; mi < 4; ++mi)
#pragma unroll
    for (int ni = 0; ni < 4; ++ni)
#pragma unroll
      for (int r = 0; r < 4; ++r)
        e[(size_t)(i0 + wm + mi * 16 + q * 4 + r) * L + (j0 + wn + ni * 16 + lr)] =
            acc[mi][ni][r];
  // --- col-max partial over this block's 128 rows for each of its 128 cols ---
  float cmax[4];
#pragma unroll
  for (int ni = 0; ni < 4; ++ni) {
    float m = acc[0][ni][0];
#pragma unroll
    for (int mi = 0; mi < 4; ++mi)
#pragma unroll
      for (int r = 0; r < 4; ++r) m = fmaxf(m, acc[mi][ni][r]);
    m = fmaxf(m, __shfl_xor(m, 16));     // fold q
    m = fmaxf(m, __shfl_xor(m, 32));
    cmax[ni] = m;                        // rows wm..wm+63, col wn+ni*16+lr
  }
  __syncthreads();                       // all waves done reading sAh before alias write
  if (!(wave & 1) && q == 0)             // waves 0 (wn=0) and 2 (wn=64)
#pragma unroll
    for (int ni = 0; ni < 4; ++ni) pcm[wn + ni * 16 + lr] = cmax[ni];
  __syncthreads();
  if ((wave & 1) && q == 0) {            // waves 1 and 3 combine row-halves
#pragma unroll
    for (int ni = 0; ni < 4; ++ni) {
      int c = wn + ni * 16 + lr;
      e[STAT + CMAXP + (size_t)(i0 >> 7) * L + j0 + c] = fmaxf(cmax[ni], pcm[c]);
    }
  }
}

// ---------------------------------------------------------------------------
// k_rowsoft: row max/sum over e; writes UNNORMALIZED exp to Pb bf16 and
// 1/rowsum to ROWINV (normalization deferred to k_pv epilogue).
// ---------------------------------------------------------------------------
__global__ __launch_bounds__(256) void k_rowsoft(float* __restrict__ ws) {
  float* slot = ws + (size_t)blockIdx.y * SLOT_F;
  const int row = blockIdx.x, tid = threadIdx.x;
  const float* er = slot + (size_t)row * L;
  float v[8]; float m = -INFINITY;
#pragma unroll
  for (int r = 0; r < 8; ++r) { v[r] = er[tid + r * 256]; m = fmaxf(m, v[r]); }
  __shared__ float red[4];
#pragma unroll
  for (int o = 32; o; o >>= 1) m = fmaxf(m, __shfl_xor(m, o));
  if ((tid & 63) == 0) red[tid >> 6] = m;
  __syncthreads();
  m = fmaxf(fmaxf(red[0], red[1]), fmaxf(red[2], red[3]));
  float ex[8], s = 0.f;
#pragma unroll
  for (int r = 0; r < 8; ++r) { ex[r] = __expf(v[r] - m); s += ex[r]; }
  __syncthreads();
#pragma unroll
  for (int o = 32; o; o >>= 1) s += __shfl_xor(s, o);
  if ((tid & 63) == 0) red[tid >> 6] = s;
  __syncthreads();
  unsigned short* P = (unsigned short*)(slot + PB_OFF) + (size_t)row * L;
#pragma unroll
  for (int r = 0; r < 8; ++r) P[tid + r * 256] = f2bf(ex[r]);
  if (tid == 0)
    slot[STAT + ROWINV + row] = 1.0f / (red[0] + red[1] + red[2] + red[3]);
}

// ---------------------------------------------------------------------------
// k_colstat2: finalize col-max from the 16 gemm-epilogue partials.
// ---------------------------------------------------------------------------
__global__ __launch_bounds__(256) void k_colstat2(float* __restrict__ ws) {
  float* st = ws + (size_t)blockIdx.y * SLOT_F + STAT;
  const int j = blockIdx.x * 256 + threadIdx.x;
  float m = st[CMAXP + j];
#pragma unroll
  for (int k = 1; k < 16; ++k) m = fmaxf(m, st[CMAXP + (size_t)k * L + j]);
  st[CMAX + j] = m;
}

// ---------------------------------------------------------------------------
// k_colexp: single read of e -> exp(v - colmax) -> transposed UNNORMALIZED
// bf16 PaT[j][i] + per-256-row-chunk partial col-sums (no atomics).
// Grid (L/64 cols, L/256 rows, nb), 256 threads.
// ---------------------------------------------------------------------------
__global__ __launch_bounds__(256) void k_colexp(float* __restrict__ ws) {
  float* slot = ws + (size_t)blockIdx.z * SLOT_F;
  const float* e = slot;
  float* st = slot + STAT;
  const int j0 = blockIdx.x * 64, i0 = blockIdx.y * 256;
  const int tid = threadIdx.x;
  const int rr = tid >> 4, c4 = (tid & 15) * 4;
  __shared__ unsigned short sT[64][72];
  __shared__ float psumL[16][64];
  float cm[4], ps[4] = {0.f, 0.f, 0.f, 0.f};
#pragma unroll
  for (int k = 0; k < 4; ++k) cm[k] = st[CMAX + j0 + c4 + k];
  unsigned short* PaT = (unsigned short*)(slot + PAT_OFF);
  for (int sub = 0; sub < 4; ++sub) {
    const int ib = i0 + sub * 64;
    __syncthreads();
#pragma unroll
    for (int p = 0; p < 4; ++p) {
      const int r = rr + p * 16;
      float4 v = *(const float4*)(e + (size_t)(ib + r) * L + j0 + c4);
      float e0 = __expf(v.x - cm[0]), e1 = __expf(v.y - cm[1]);
      float e2 = __expf(v.z - cm[2]), e3 = __expf(v.w - cm[3]);
      ps[0] += e0; ps[1] += e1; ps[2] += e2; ps[3] += e3;
      sT[c4 + 0][r] = f2bf(e0); sT[c4 + 1][r] = f2bf(e1);
      sT[c4 + 2][r] = f2bf(e2); sT[c4 + 3][r] = f2bf(e3);
    }
    __syncthreads();
    const int cc = tid >> 2, qd = tid & 3;
    uint4 o0 = *(const uint4*)&sT[cc][qd * 8];
    uint4 o1 = *(const uint4*)&sT[cc][32 + qd * 8];
    *(uint4*)&PaT[(size_t)(j0 + cc) * L + ib + qd * 8] = o0;
    *(uint4*)&PaT[(size_t)(j0 + cc) * L + ib + 32 + qd * 8] = o1;
  }
  psumL[rr][c4 + 0] = ps[0]; psumL[rr][c4 + 1] = ps[1];
  psumL[rr][c4 + 2] = ps[2]; psumL[rr][c4 + 3] = ps[3];
  __syncthreads();
  if (tid < 64) {
    float s = 0.f;
#pragma unroll
    for (int g = 0; g < 16; ++g) s += psumL[g][tid];
    st[CSUMP + (size_t)blockIdx.y * L + j0 + tid] = s;
  }
}

// ---------------------------------------------------------------------------
// k_colfin: 1/colsum from the 8 partials.
// ---------------------------------------------------------------------------
__global__ __launch_bounds__(256) void k_colfin(float* __restrict__ ws) {
  float* st = ws + (size_t)blockIdx.y * SLOT_F + STAT;
  const int j = blockIdx.x * 256 + threadIdx.x;
  float s = 0.f;
#pragma unroll
  for (int k = 0; k < 8; ++k) s += st[CSUMP + (size_t)k * L + j];
  st[CINV + j] = 1.0f / s;
}

// ---------------------------------------------------------------------------
// k_pv (merged): out[m][d] = inv[m] * sum_k P[m][k] * W[d][k].
// pair = z>=nb selects {Pb, bt, out0, ROWINV} vs {PaT, at, out1, CINV}.
// BK=64 (32 MFMA per barrier-pair); XOR-swizzled LDS (pre-swizzled global
// source + swizzled fragment reads; rule #21).
// ---------------------------------------------------------------------------
__global__ __launch_bounds__(256) void k_pv(const unsigned short* __restrict__ at,
                                            const unsigned short* __restrict__ bt,
                                            float* __restrict__ ws,
                                            float* __restrict__ outB,
                                            int b0, int nb) {
  const int z = blockIdx.z;
  const int pair = (z >= nb) ? 1 : 0;
  const int bz = z - pair * nb;
  const int batch = b0 + bz;
  float* slot = ws + (size_t)bz * SLOT_F;
  const unsigned short* P =
      (const unsigned short*)(slot + (pair ? PAT_OFF : PB_OFF));
  const unsigned short* W = (pair ? at : bt) + (size_t)batch * D * L;
  float* out = outB + (size_t)(pair * BATCH + batch) * L * D;
  const float* sc = slot + STAT + (pair ? CINV : ROWINV);
  const int m0 = blockIdx.x * 128, d0 = blockIdx.y * 128;
  __shared__ unsigned short sP[128 * 64], sW[128 * 64];
  const int tid = threadIdx.x, lane = tid & 63, wave = tid >> 6;
  const int wm = (wave & 1) * 64, wn = (wave >> 1) * 64;
  const int q = lane >> 4, lr = lane & 15;
  // staging: lane's LDS slot (linear) = row*64 + (lane&7)*8 ushorts,
  // row = wave*8 + (lane>>3); source col pre-swizzled by XOR (row&7)*8.
  const int srow = wave * 8 + (lane >> 3);
  const int scolu = ((lane & 7) ^ (lane >> 3)) * 8;
  const size_t gp = (size_t)(m0 + srow) * L + scolu;
  const size_t gw = (size_t)(d0 + srow) * L + scolu;
  const int ldsb = wave * 512;
  const int swz = (lr & 7) << 3;
  f32x4 acc[4][4] = {};
  for (int k0 = 0; k0 < L; k0 += 64) {
    __syncthreads();
#pragma unroll
    for (int it = 0; it < 4; ++it) {
      GLL16(P + gp + (size_t)it * 32 * L + k0, sP + ldsb + it * 2048);
      GLL16(W + gw + (size_t)it * 32 * L + k0, sW + ldsb + it * 2048);
    }
    __syncthreads();
#pragma unroll
    for (int kk = 0; kk < 2; ++kk) {
      bf16x8 fa[4], fb[4];
#pragma unroll
      for (int t = 0; t < 4; ++t) {
        fa[t] = *(const bf16x8*)&sP[(wm + t * 16 + lr) * 64 + ((kk * 32 + q * 8) ^ swz)];
        fb[t] = *(const bf16x8*)&sW[(wn + t * 16 + lr) * 64 + ((kk * 32 + q * 8) ^ swz)];
      }
#pragma unroll
      for (int mi = 0; mi < 4; ++mi)
#pragma unroll
        for (int ni = 0; ni < 4; ++ni)
          acc[mi][ni] = __builtin_amdgcn_mfma_f32_16x16x32_bf16(fa[mi], fb[ni], acc[mi][ni], 0, 0, 0);
    }
  }
  float rsc[4][4];
#pragma unroll
  for (int mi = 0; mi < 4; ++mi)
#pragma unroll
    for (int r = 0; r < 4; ++r)
      rsc[mi][r] = sc[m0 + wm + mi * 16 + q * 4 + r];
#pragma unroll
  for (int mi = 0; mi < 4; ++mi)
#pragma unroll
    for (int ni = 0; ni < 4; ++ni)
#pragma unroll
      for (int r = 0; r < 4; ++r)
        out[(size_t)(m0 + wm + mi * 16 + q * 4 + r) * D + (d0 + wn + ni * 16 + lr)] =
            acc[mi][ni][r] * rsc[mi][r];
}

extern "C" void kernel_launch(void* const* d_in, const int* in_sizes, int n_in,
                              void* d_out, int out_size, void* d_ws, size_t ws_size,
                              hipStream_t stream) {
  const float* a = (const float*)d_in[0];
  const float* b = (const float*)d_in[1];
  float* out = (float*)d_out;
  const size_t PL = (size_t)BATCH * D * L;
  unsigned short* at = (unsigned short*)d_ws;
  unsigned short* bt = at + PL;
  unsigned short* ah = bt + PL;
  unsigned short* al = ah + PL;
  unsigned short* bh = al + PL;
  unsigned short* bl = bh + PL;
  float* slots = (float*)(bl + PL);
  const size_t base_bytes = 6 * PL * sizeof(unsigned short);
  const size_t slot_bytes = (size_t)SLOT_F * sizeof(float);
  int S = 1;
  if (ws_size > base_bytes + slot_bytes)
    S = (int)((ws_size - base_bytes) / slot_bytes);
  if (S > BATCH) S = BATCH;
  if (S < 1) S = 1;

  hipLaunchKernelGGL(k_prep, dim3(L / 64, D / 64, 2 * BATCH), dim3(256), 0, stream,
                     a, b, at, bt, ah, al, bh, bl);
  for (int b0 = 0; b0 < BATCH; b0 += S) {
    int nb = (BATCH - b0 < S) ? (BATCH - b0) : S;
    hipLaunchKernelGGL(k_gemm_e, dim3(16, 16, nb), dim3(256), 0, stream,
                       ah, al, bh, bl, slots, b0);
    hipLaunchKernelGGL(k_rowsoft, dim3(L, nb), dim3(256), 0, stream, slots);
    hipLaunchKernelGGL(k_colstat2, dim3(L / 256, nb), dim3(256), 0, stream, slots);
    hipLaunchKernelGGL(k_colexp, dim3(L / 64, L / 256, nb), dim3(256), 0, stream, slots);
    hipLaunchKernelGGL(k_colfin, dim3(L / 256, nb), dim3(256), 0, stream, slots);
    hipLaunchKernelGGL(k_pv, dim3(16, 8, 2 * nb), dim3(256), 0, stream,
                       at, bt, slots, out, b0, nb);
  }
}

// Round 5
// 720.462 us; speedup vs baseline: 1.0268x; 1.0268x over previous
//
#include <hip/hip_runtime.h>

#define BATCH 8
#define L 2048
#define D 1024

// ws layout:
//  [ at : B*D*L bf16 ][ bt : B*D*L bf16 ]            (transposed single-bf16, W operands)
//  [ ah ][ al ][ bh ][ bl ] : B*L*D bf16 each        (hi/lo split planes, row-major [i][d])
//  [ slots... ] each slot (float units):
//    e (L*L fp32) | Pb (L*L bf16, unnorm) | PaT (L*L bf16, unnorm) | stats (28*L f32)
#define PB_OFF  (L * L)
#define PAT_OFF (L * L + (L * L) / 2)
#define STAT    (2 * L * L)
// stat sub-offsets (floats, relative to slot+STAT)
#define ROWINV  0            // L       1/rowsum (from k_rowsoft)
#define CMAXP   (L)          // 8*L     partial col-max per 256-row chunk (from k_colmax)
#define CMAX    (17 * L)     // L       final col-max
#define CSUMP   (18 * L)     // 8*L     partial col-sums per 256-row chunk
#define CINV    (26 * L)     // L       1/colsum
#define SLOT_F  (2 * L * L + 28 * L)

typedef __attribute__((ext_vector_type(8))) short bf16x8;
typedef __attribute__((ext_vector_type(4))) float f32x4;

static __device__ inline unsigned short f2bf(float x) {
  union { float f; unsigned u; } v; v.f = x;
  unsigned r = v.u + 0x7fff + ((v.u >> 16) & 1);   // RNE (inputs finite)
  return (unsigned short)(r >> 16);
}
static __device__ inline float bf2f(unsigned short h) {
  union { unsigned u; float f; } v; v.u = ((unsigned)h) << 16; return v.f;
}
static __device__ inline unsigned pack2(float x, float y) {
  return (unsigned)f2bf(x) | ((unsigned)f2bf(y) << 16);
}
static __device__ inline void split2(float x, float y, unsigned &hi, unsigned &lo) {
  unsigned short hx = f2bf(x), hy = f2bf(y);
  float rx = x - bf2f(hx), ry = y - bf2f(hy);
  hi = (unsigned)hx | ((unsigned)hy << 16);
  lo = (unsigned)f2bf(rx) | ((unsigned)f2bf(ry) << 16);
}

#define GLL16(gp, lp) __builtin_amdgcn_global_load_lds(                        \
    (const __attribute__((address_space(1))) void*)(gp),                       \
    (__attribute__((address_space(3))) void*)(lp), 16, 0, 0)

// Stage one 128x32 bf16 tile (8 KiB) global->LDS, linear layout [128][32].
static __device__ inline void stage2(const unsigned short* __restrict__ g,
                                     size_t o0, size_t o1,
                                     unsigned short* l, int wb) {
  GLL16(g + o0, l + wb);
  GLL16(g + o1, l + wb + 2048);
}

// ---------------------------------------------------------------------------
// k_prep: at[b][d][i] = bf16(a[b][i][d]) (and bt from b) for the PV W-operand;
// plus hi/lo split planes ah/al (bh/bl) row-major [i][d].
// ---------------------------------------------------------------------------
__global__ __launch_bounds__(256) void k_prep(const float* __restrict__ A,
                                              const float* __restrict__ Bm,
                                              unsigned short* __restrict__ at,
                                              unsigned short* __restrict__ bt,
                                              unsigned short* __restrict__ ah,
                                              unsigned short* __restrict__ al,
                                              unsigned short* __restrict__ bh,
                                              unsigned short* __restrict__ bl) {
  const int z = blockIdx.z, batch = z & 7;
  const bool isA = z < 8;
  const float* src = (isA ? A : Bm) + (size_t)batch * L * D;
  unsigned short* dst = (isA ? at : bt) + (size_t)batch * D * L;
  unsigned short* ph = (isA ? ah : bh) + (size_t)batch * L * D;
  unsigned short* pl = (isA ? al : bl) + (size_t)batch * L * D;
  const int i0 = blockIdx.x * 64, d0 = blockIdx.y * 64;
  __shared__ float sT[64][65];
  const int tid = threadIdx.x;
#pragma unroll
  for (int it = 0; it < 4; ++it) {
    int idx = tid + it * 256;
    int row = idx >> 4, c4 = (idx & 15) * 4;
    float4 v = *(const float4*)(src + (size_t)(i0 + row) * D + d0 + c4);
    unsigned h0, l0, h1, l1;
    split2(v.x, v.y, h0, l0); split2(v.z, v.w, h1, l1);
    size_t po = (size_t)(i0 + row) * D + d0 + c4;
    *(uint2*)&ph[po] = make_uint2(h0, h1);
    *(uint2*)&pl[po] = make_uint2(l0, l1);
    sT[row][c4 + 0] = v.x; sT[row][c4 + 1] = v.y;
    sT[row][c4 + 2] = v.z; sT[row][c4 + 3] = v.w;
  }
  __syncthreads();
#pragma unroll
  for (int it = 0; it < 4; ++it) {
    int idx = tid + it * 256;
    int orow = idx >> 4, c4 = (idx & 15) * 4;
    uint2 o = make_uint2(pack2(sT[c4 + 0][orow], sT[c4 + 1][orow]),
                         pack2(sT[c4 + 2][orow], sT[c4 + 3][orow]));
    *(uint2*)&dst[(size_t)(d0 + orow) * L + i0 + c4] = o;
  }
}

// ---------------------------------------------------------------------------
// Kernel 1: e = a @ b^T (split-bf16: hh + hl + lh) from pre-split planes.
// 128x128 tile, BK=32, global_load_lds staging — EXACT R1 body (212 us,
// VGPR 80, MfmaUtil 44%). Col-max stats moved to k_colmax (the R2/R3
// "free" epilogue cost +42 us via VGPR 80->88 / schedule perturbation).
// ---------------------------------------------------------------------------
__global__ __launch_bounds__(256) void k_gemm_e(const unsigned short* __restrict__ ah,
                                                const unsigned short* __restrict__ al,
                                                const unsigned short* __restrict__ bh,
                                                const unsigned short* __restrict__ bl,
                                                float* __restrict__ ws, int b0) {
  const int bz = blockIdx.z, batch = b0 + bz;
  const size_t po = (size_t)batch * L * D;
  float* e = ws + (size_t)bz * SLOT_F;
  const int i0 = blockIdx.x * 128, j0 = blockIdx.y * 128;
  __shared__ unsigned short sAh[128 * 32], sAl[128 * 32];
  __shared__ unsigned short sBh[128 * 32], sBl[128 * 32];
  const int tid = threadIdx.x, lane = tid & 63, wave = tid >> 6;
  const int wm = (wave & 1) * 64, wn = (wave >> 1) * 64;
  const int q = lane >> 4, lr = lane & 15;
  const int soff = wave * 1024 + lane * 16;
  const int srow = soff >> 6, scol = (soff & 63) >> 1;
  const int wb = wave * 512;
  const unsigned short* gAh = ah + po; const unsigned short* gAl = al + po;
  const unsigned short* gBh = bh + po; const unsigned short* gBl = bl + po;
  const size_t ga0 = (size_t)(i0 + srow) * D + scol, ga1 = ga0 + (size_t)64 * D;
  const size_t gb0 = (size_t)(j0 + srow) * D + scol, gb1 = gb0 + (size_t)64 * D;
  f32x4 acc[4][4] = {};
  for (int k0 = 0; k0 < D; k0 += 32) {
    __syncthreads();
    stage2(gAh, ga0 + k0, ga1 + k0, sAh, wb);
    stage2(gAl, ga0 + k0, ga1 + k0, sAl, wb);
    stage2(gBh, gb0 + k0, gb1 + k0, sBh, wb);
    stage2(gBl, gb0 + k0, gb1 + k0, sBl, wb);
    __syncthreads();
    bf16x8 fah[4], fbh[4], fx[4];
#pragma unroll
    for (int t = 0; t < 4; ++t) {
      fah[t] = *(const bf16x8*)&sAh[(wm + t * 16 + lr) * 32 + q * 8];
      fbh[t] = *(const bf16x8*)&sBh[(wn + t * 16 + lr) * 32 + q * 8];
    }
#pragma unroll
    for (int mi = 0; mi < 4; ++mi)
#pragma unroll
      for (int ni = 0; ni < 4; ++ni)
        acc[mi][ni] = __builtin_amdgcn_mfma_f32_16x16x32_bf16(fah[mi], fbh[ni], acc[mi][ni], 0, 0, 0);
#pragma unroll
    for (int t = 0; t < 4; ++t)
      fx[t] = *(const bf16x8*)&sBl[(wn + t * 16 + lr) * 32 + q * 8];
#pragma unroll
    for (int mi = 0; mi < 4; ++mi)
#pragma unroll
      for (int ni = 0; ni < 4; ++ni)
        acc[mi][ni] = __builtin_amdgcn_mfma_f32_16x16x32_bf16(fah[mi], fx[ni], acc[mi][ni], 0, 0, 0);
#pragma unroll
    for (int t = 0; t < 4; ++t)
      fx[t] = *(const bf16x8*)&sAl[(wm + t * 16 + lr) * 32 + q * 8];
#pragma unroll
    for (int mi = 0; mi < 4; ++mi)
#pragma unroll
      for (int ni = 0; ni < 4; ++ni)
        acc[mi][ni] = __builtin_amdgcn_mfma_f32_16x16x32_bf16(fx[mi], fbh[ni], acc[mi][ni], 0, 0, 0);
  }
#pragma unroll
  for (int mi = 0; mi < 4; ++mi)
#pragma unroll
    for (int ni = 0; ni < 4; ++ni)
#pragma unroll
      for (int r = 0; r < 4; ++r)
        e[(size_t)(i0 + wm + mi * 16 + q * 4 + r) * L + (j0 + wn + ni * 16 + lr)] =
            acc[mi][ni][r];
}

// ---------------------------------------------------------------------------
// k_rowsoft: row max/sum over e; writes UNNORMALIZED exp to Pb bf16 and
// 1/rowsum to ROWINV (normalization deferred to k_pv epilogue).
// ---------------------------------------------------------------------------
__global__ __launch_bounds__(256) void k_rowsoft(float* __restrict__ ws) {
  float* slot = ws + (size_t)blockIdx.y * SLOT_F;
  const int row = blockIdx.x, tid = threadIdx.x;
  const float* er = slot + (size_t)row * L;
  float v[8]; float m = -INFINITY;
#pragma unroll
  for (int r = 0; r < 8; ++r) { v[r] = er[tid + r * 256]; m = fmaxf(m, v[r]); }
  __shared__ float red[4];
#pragma unroll
  for (int o = 32; o; o >>= 1) m = fmaxf(m, __shfl_xor(m, o));
  if ((tid & 63) == 0) red[tid >> 6] = m;
  __syncthreads();
  m = fmaxf(fmaxf(red[0], red[1]), fmaxf(red[2], red[3]));
  float ex[8], s = 0.f;
#pragma unroll
  for (int r = 0; r < 8; ++r) { ex[r] = __expf(v[r] - m); s += ex[r]; }
  __syncthreads();
#pragma unroll
  for (int o = 32; o; o >>= 1) s += __shfl_xor(s, o);
  if ((tid & 63) == 0) red[tid >> 6] = s;
  __syncthreads();
  unsigned short* P = (unsigned short*)(slot + PB_OFF) + (size_t)row * L;
#pragma unroll
  for (int r = 0; r < 8; ++r) P[tid + r * 256] = f2bf(ex[r]);
  if (tid == 0)
    slot[STAT + ROWINV + row] = 1.0f / (red[0] + red[1] + red[2] + red[3]);
}

// ---------------------------------------------------------------------------
// k_colmax: partial col-max over 256-row chunks of e (coalesced float4 rows).
// Grid (L/64 cols, L/256 rows, nb), 256 threads. Writes CMAXP[chunk][j].
// ---------------------------------------------------------------------------
__global__ __launch_bounds__(256) void k_colmax(float* __restrict__ ws) {
  float* slot = ws + (size_t)blockIdx.z * SLOT_F;
  const float* e = slot;
  float* st = slot + STAT;
  const int j0 = blockIdx.x * 64, i0 = blockIdx.y * 256;
  const int tid = threadIdx.x;
  const int rr = tid >> 4, c4 = (tid & 15) * 4;   // 16 row-groups x 16 col-quads
  float m0 = -INFINITY, m1 = -INFINITY, m2 = -INFINITY, m3 = -INFINITY;
#pragma unroll 4
  for (int i = rr; i < 256; i += 16) {
    float4 v = *(const float4*)(e + (size_t)(i0 + i) * L + j0 + c4);
    m0 = fmaxf(m0, v.x); m1 = fmaxf(m1, v.y);
    m2 = fmaxf(m2, v.z); m3 = fmaxf(m3, v.w);
  }
  __shared__ float red[16][64];
  red[rr][c4 + 0] = m0; red[rr][c4 + 1] = m1;
  red[rr][c4 + 2] = m2; red[rr][c4 + 3] = m3;
  __syncthreads();
  if (tid < 64) {
    float m = red[0][tid];
#pragma unroll
    for (int g = 1; g < 16; ++g) m = fmaxf(m, red[g][tid]);
    st[CMAXP + (size_t)blockIdx.y * L + j0 + tid] = m;
  }
}

// ---------------------------------------------------------------------------
// k_colstat2: finalize col-max from the 8 k_colmax partials.
// ---------------------------------------------------------------------------
__global__ __launch_bounds__(256) void k_colstat2(float* __restrict__ ws) {
  float* st = ws + (size_t)blockIdx.y * SLOT_F + STAT;
  const int j = blockIdx.x * 256 + threadIdx.x;
  float m = st[CMAXP + j];
#pragma unroll
  for (int k = 1; k < 8; ++k) m = fmaxf(m, st[CMAXP + (size_t)k * L + j]);
  st[CMAX + j] = m;
}

// ---------------------------------------------------------------------------
// k_colexp: single read of e -> exp(v - colmax) -> transposed UNNORMALIZED
// bf16 PaT[j][i] + per-256-row-chunk partial col-sums (no atomics).
// Grid (L/64 cols, L/256 rows, nb), 256 threads.
// ---------------------------------------------------------------------------
__global__ __launch_bounds__(256) void k_colexp(float* __restrict__ ws) {
  float* slot = ws + (size_t)blockIdx.z * SLOT_F;
  const float* e = slot;
  float* st = slot + STAT;
  const int j0 = blockIdx.x * 64, i0 = blockIdx.y * 256;
  const int tid = threadIdx.x;
  const int rr = tid >> 4, c4 = (tid & 15) * 4;
  __shared__ unsigned short sT[64][72];
  __shared__ float psumL[16][64];
  float cm[4], ps[4] = {0.f, 0.f, 0.f, 0.f};
#pragma unroll
  for (int k = 0; k < 4; ++k) cm[k] = st[CMAX + j0 + c4 + k];
  unsigned short* PaT = (unsigned short*)(slot + PAT_OFF);
  for (int sub = 0; sub < 4; ++sub) {
    const int ib = i0 + sub * 64;
    __syncthreads();
#pragma unroll
    for (int p = 0; p < 4; ++p) {
      const int r = rr + p * 16;
      float4 v = *(const float4*)(e + (size_t)(ib + r) * L + j0 + c4);
      float e0 = __expf(v.x - cm[0]), e1 = __expf(v.y - cm[1]);
      float e2 = __expf(v.z - cm[2]), e3 = __expf(v.w - cm[3]);
      ps[0] += e0; ps[1] += e1; ps[2] += e2; ps[3] += e3;
      sT[c4 + 0][r] = f2bf(e0); sT[c4 + 1][r] = f2bf(e1);
      sT[c4 + 2][r] = f2bf(e2); sT[c4 + 3][r] = f2bf(e3);
    }
    __syncthreads();
    const int cc = tid >> 2, qd = tid & 3;
    uint4 o0 = *(const uint4*)&sT[cc][qd * 8];
    uint4 o1 = *(const uint4*)&sT[cc][32 + qd * 8];
    *(uint4*)&PaT[(size_t)(j0 + cc) * L + ib + qd * 8] = o0;
    *(uint4*)&PaT[(size_t)(j0 + cc) * L + ib + 32 + qd * 8] = o1;
  }
  psumL[rr][c4 + 0] = ps[0]; psumL[rr][c4 + 1] = ps[1];
  psumL[rr][c4 + 2] = ps[2]; psumL[rr][c4 + 3] = ps[3];
  __syncthreads();
  if (tid < 64) {
    float s = 0.f;
#pragma unroll
    for (int g = 0; g < 16; ++g) s += psumL[g][tid];
    st[CSUMP + (size_t)blockIdx.y * L + j0 + tid] = s;
  }
}

// ---------------------------------------------------------------------------
// k_colfin: 1/colsum from the 8 partials.
// ---------------------------------------------------------------------------
__global__ __launch_bounds__(256) void k_colfin(float* __restrict__ ws) {
  float* st = ws + (size_t)blockIdx.y * SLOT_F + STAT;
  const int j = blockIdx.x * 256 + threadIdx.x;
  float s = 0.f;
#pragma unroll
  for (int k = 0; k < 8; ++k) s += st[CSUMP + (size_t)k * L + j];
  st[CINV + j] = 1.0f / s;
}

// ---------------------------------------------------------------------------
// k_pv (merged): out[m][d] = inv[m] * sum_k P[m][k] * W[d][k].
// pair = z>=nb selects {Pb, bt, out0, ROWINV} vs {PaT, at, out1, CINV}.
// BK=64 (32 MFMA per barrier-pair); XOR-swizzled LDS (pre-swizzled global
// source + swizzled fragment reads; rule #21).
// ---------------------------------------------------------------------------
__global__ __launch_bounds__(256) void k_pv(const unsigned short* __restrict__ at,
                                            const unsigned short* __restrict__ bt,
                                            float* __restrict__ ws,
                                            float* __restrict__ outB,
                                            int b0, int nb) {
  const int z = blockIdx.z;
  const int pair = (z >= nb) ? 1 : 0;
  const int bz = z - pair * nb;
  const int batch = b0 + bz;
  float* slot = ws + (size_t)bz * SLOT_F;
  const unsigned short* P =
      (const unsigned short*)(slot + (pair ? PAT_OFF : PB_OFF));
  const unsigned short* W = (pair ? at : bt) + (size_t)batch * D * L;
  float* out = outB + (size_t)(pair * BATCH + batch) * L * D;
  const float* sc = slot + STAT + (pair ? CINV : ROWINV);
  const int m0 = blockIdx.x * 128, d0 = blockIdx.y * 128;
  __shared__ unsigned short sP[128 * 64], sW[128 * 64];
  const int tid = threadIdx.x, lane = tid & 63, wave = tid >> 6;
  const int wm = (wave & 1) * 64, wn = (wave >> 1) * 64;
  const int q = lane >> 4, lr = lane & 15;
  // staging: lane's LDS slot (linear) = row*64 + (lane&7)*8 ushorts,
  // row = wave*8 + (lane>>3); source col pre-swizzled by XOR (row&7)*8.
  const int srow = wave * 8 + (lane >> 3);
  const int scolu = ((lane & 7) ^ (lane >> 3)) * 8;
  const size_t gp = (size_t)(m0 + srow) * L + scolu;
  const size_t gw = (size_t)(d0 + srow) * L + scolu;
  const int ldsb = wave * 512;
  const int swz = (lr & 7) << 3;
  f32x4 acc[4][4] = {};
  for (int k0 = 0; k0 < L; k0 += 64) {
    __syncthreads();
#pragma unroll
    for (int it = 0; it < 4; ++it) {
      GLL16(P + gp + (size_t)it * 32 * L + k0, sP + ldsb + it * 2048);
      GLL16(W + gw + (size_t)it * 32 * L + k0, sW + ldsb + it * 2048);
    }
    __syncthreads();
#pragma unroll
    for (int kk = 0; kk < 2; ++kk) {
      bf16x8 fa[4], fb[4];
#pragma unroll
      for (int t = 0; t < 4; ++t) {
        fa[t] = *(const bf16x8*)&sP[(wm + t * 16 + lr) * 64 + ((kk * 32 + q * 8) ^ swz)];
        fb[t] = *(const bf16x8*)&sW[(wn + t * 16 + lr) * 64 + ((kk * 32 + q * 8) ^ swz)];
      }
#pragma unroll
      for (int mi = 0; mi < 4; ++mi)
#pragma unroll
        for (int ni = 0; ni < 4; ++ni)
          acc[mi][ni] = __builtin_amdgcn_mfma_f32_16x16x32_bf16(fa[mi], fb[ni], acc[mi][ni], 0, 0, 0);
    }
  }
  float rsc[4][4];
#pragma unroll
  for (int mi = 0; mi < 4; ++mi)
#pragma unroll
    for (int r = 0; r < 4; ++r)
      rsc[mi][r] = sc[m0 + wm + mi * 16 + q * 4 + r];
#pragma unroll
  for (int mi = 0; mi < 4; ++mi)
#pragma unroll
    for (int ni = 0; ni < 4; ++ni)
#pragma unroll
      for (int r = 0; r < 4; ++r)
        out[(size_t)(m0 + wm + mi * 16 + q * 4 + r) * D + (d0 + wn + ni * 16 + lr)] =
            acc[mi][ni][r] * rsc[mi][r];
}

extern "C" void kernel_launch(void* const* d_in, const int* in_sizes, int n_in,
                              void* d_out, int out_size, void* d_ws, size_t ws_size,
                              hipStream_t stream) {
  const float* a = (const float*)d_in[0];
  const float* b = (const float*)d_in[1];
  float* out = (float*)d_out;
  const size_t PL = (size_t)BATCH * D * L;
  unsigned short* at = (unsigned short*)d_ws;
  unsigned short* bt = at + PL;
  unsigned short* ah = bt + PL;
  unsigned short* al = ah + PL;
  unsigned short* bh = al + PL;
  unsigned short* bl = bh + PL;
  float* slots = (float*)(bl + PL);
  const size_t base_bytes = 6 * PL * sizeof(unsigned short);
  const size_t slot_bytes = (size_t)SLOT_F * sizeof(float);
  int S = 1;
  if (ws_size > base_bytes + slot_bytes)
    S = (int)((ws_size - base_bytes) / slot_bytes);
  if (S > BATCH) S = BATCH;
  if (S < 1) S = 1;

  hipLaunchKernelGGL(k_prep, dim3(L / 64, D / 64, 2 * BATCH), dim3(256), 0, stream,
                     a, b, at, bt, ah, al, bh, bl);
  for (int b0 = 0; b0 < BATCH; b0 += S) {
    int nb = (BATCH - b0 < S) ? (BATCH - b0) : S;
    hipLaunchKernelGGL(k_gemm_e, dim3(16, 16, nb), dim3(256), 0, stream,
                       ah, al, bh, bl, slots, b0);
    hipLaunchKernelGGL(k_rowsoft, dim3(L, nb), dim3(256), 0, stream, slots);
    hipLaunchKernelGGL(k_colmax, dim3(L / 64, L / 256, nb), dim3(256), 0, stream, slots);
    hipLaunchKernelGGL(k_colstat2, dim3(L / 256, nb), dim3(256), 0, stream, slots);
    hipLaunchKernelGGL(k_colexp, dim3(L / 64, L / 256, nb), dim3(256), 0, stream, slots);
    hipLaunchKernelGGL(k_colfin, dim3(L / 256, nb), dim3(256), 0, stream, slots);
    hipLaunchKernelGGL(k_pv, dim3(16, 8, 2 * nb), dim3(256), 0, stream,
                       at, bt, slots, out, b0, nb);
  }
}

// Round 7
// 718.058 us; speedup vs baseline: 1.0303x; 1.0033x over previous
//
#include <hip/hip_runtime.h>

#define BATCH 8
#define L 2048
#define D 1024

// ws layout:
//  [ at : B*D*L bf16 ][ bt : B*D*L bf16 ]            (transposed single-bf16, W operands)
//  [ ah ][ al ][ bh ][ bl ] : B*L*D bf16 each        (hi/lo split planes, row-major [i][d])
//  [ slots... ] each slot (float units):
//    e (L*L fp32) | Pb (L*L bf16, unnorm) | PaT (L*L bf16, unnorm) | stats (28*L f32)
#define PB_OFF  (L * L)
#define PAT_OFF (L * L + (L * L) / 2)
#define STAT    (2 * L * L)
// stat sub-offsets (floats, relative to slot+STAT)
#define ROWINV  0            // L       1/rowsum (from k_rowsoft)
#define CMAXP   (L)          // 8*L     partial col-max per 256-row chunk (from k_colmax)
#define CSUMP   (18 * L)     // 8*L     partial col-sums per 256-row chunk (from k_colexp)
#define SLOT_F  (2 * L * L + 28 * L)

typedef __attribute__((ext_vector_type(8))) short bf16x8;
typedef __attribute__((ext_vector_type(4))) float f32x4;

static __device__ inline unsigned short f2bf(float x) {
  union { float f; unsigned u; } v; v.f = x;
  unsigned r = v.u + 0x7fff + ((v.u >> 16) & 1);   // RNE (inputs finite)
  return (unsigned short)(r >> 16);
}
static __device__ inline float bf2f(unsigned short h) {
  union { unsigned u; float f; } v; v.u = ((unsigned)h) << 16; return v.f;
}
static __device__ inline unsigned pack2(float x, float y) {
  return (unsigned)f2bf(x) | ((unsigned)f2bf(y) << 16);
}
static __device__ inline void split2(float x, float y, unsigned &hi, unsigned &lo) {
  unsigned short hx = f2bf(x), hy = f2bf(y);
  float rx = x - bf2f(hx), ry = y - bf2f(hy);
  hi = (unsigned)hx | ((unsigned)hy << 16);
  lo = (unsigned)f2bf(rx) | ((unsigned)f2bf(ry) << 16);
}

#define GLL16(gp, lp) __builtin_amdgcn_global_load_lds(                        \
    (const __attribute__((address_space(1))) void*)(gp),                       \
    (__attribute__((address_space(3))) void*)(lp), 16, 0, 0)

// Stage one 128x32 bf16 tile (8 KiB) global->LDS, linear layout [128][32].
static __device__ inline void stage2(const unsigned short* __restrict__ g,
                                     size_t o0, size_t o1,
                                     unsigned short* l, int wb) {
  GLL16(g + o0, l + wb);
  GLL16(g + o1, l + wb + 2048);
}

// ---------------------------------------------------------------------------
// k_prep: at[b][d][i] = bf16(a[b][i][d]) (and bt from b) for the PV W-operand;
// plus hi/lo split planes ah/al (bh/bl) row-major [i][d].
// ---------------------------------------------------------------------------
__global__ __launch_bounds__(256) void k_prep(const float* __restrict__ A,
                                              const float* __restrict__ Bm,
                                              unsigned short* __restrict__ at,
                                              unsigned short* __restrict__ bt,
                                              unsigned short* __restrict__ ah,
                                              unsigned short* __restrict__ al,
                                              unsigned short* __restrict__ bh,
                                              unsigned short* __restrict__ bl) {
  const int z = blockIdx.z, batch = z & 7;
  const bool isA = z < 8;
  const float* src = (isA ? A : Bm) + (size_t)batch * L * D;
  unsigned short* dst = (isA ? at : bt) + (size_t)batch * D * L;
  unsigned short* ph = (isA ? ah : bh) + (size_t)batch * L * D;
  unsigned short* pl = (isA ? al : bl) + (size_t)batch * L * D;
  const int i0 = blockIdx.x * 64, d0 = blockIdx.y * 64;
  __shared__ float sT[64][65];
  const int tid = threadIdx.x;
#pragma unroll
  for (int it = 0; it < 4; ++it) {
    int idx = tid + it * 256;
    int row = idx >> 4, c4 = (idx & 15) * 4;
    float4 v = *(const float4*)(src + (size_t)(i0 + row) * D + d0 + c4);
    unsigned h0, l0, h1, l1;
    split2(v.x, v.y, h0, l0); split2(v.z, v.w, h1, l1);
    size_t po = (size_t)(i0 + row) * D + d0 + c4;
    *(uint2*)&ph[po] = make_uint2(h0, h1);
    *(uint2*)&pl[po] = make_uint2(l0, l1);
    sT[row][c4 + 0] = v.x; sT[row][c4 + 1] = v.y;
    sT[row][c4 + 2] = v.z; sT[row][c4 + 3] = v.w;
  }
  __syncthreads();
#pragma unroll
  for (int it = 0; it < 4; ++it) {
    int idx = tid + it * 256;
    int orow = idx >> 4, c4 = (idx & 15) * 4;
    uint2 o = make_uint2(pack2(sT[c4 + 0][orow], sT[c4 + 1][orow]),
                         pack2(sT[c4 + 2][orow], sT[c4 + 3][orow]));
    *(uint2*)&dst[(size_t)(d0 + orow) * L + i0 + c4] = o;
  }
}

// ---------------------------------------------------------------------------
// Kernel 1: e = a @ b^T (split-bf16: hh + hl + lh) from pre-split planes.
// 128x128 tile, BK=32, global_load_lds staging — EXACT R1 body (212 us,
// VGPR 80, MfmaUtil 44%). Stats live in k_colmax (R5 confirmed the fused
// epilogue cost +40 us via VGPR/schedule perturbation).
// ---------------------------------------------------------------------------
__global__ __launch_bounds__(256) void k_gemm_e(const unsigned short* __restrict__ ah,
                                                const unsigned short* __restrict__ al,
                                                const unsigned short* __restrict__ bh,
                                                const unsigned short* __restrict__ bl,
                                                float* __restrict__ ws, int b0) {
  const int bz = blockIdx.z, batch = b0 + bz;
  const size_t po = (size_t)batch * L * D;
  float* e = ws + (size_t)bz * SLOT_F;
  const int i0 = blockIdx.x * 128, j0 = blockIdx.y * 128;
  __shared__ unsigned short sAh[128 * 32], sAl[128 * 32];
  __shared__ unsigned short sBh[128 * 32], sBl[128 * 32];
  const int tid = threadIdx.x, lane = tid & 63, wave = tid >> 6;
  const int wm = (wave & 1) * 64, wn = (wave >> 1) * 64;
  const int q = lane >> 4, lr = lane & 15;
  const int soff = wave * 1024 + lane * 16;
  const int srow = soff >> 6, scol = (soff & 63) >> 1;
  const int wb = wave * 512;
  const unsigned short* gAh = ah + po; const unsigned short* gAl = al + po;
  const unsigned short* gBh = bh + po; const unsigned short* gBl = bl + po;
  const size_t ga0 = (size_t)(i0 + srow) * D + scol, ga1 = ga0 + (size_t)64 * D;
  const size_t gb0 = (size_t)(j0 + srow) * D + scol, gb1 = gb0 + (size_t)64 * D;
  f32x4 acc[4][4] = {};
  for (int k0 = 0; k0 < D; k0 += 32) {
    __syncthreads();
    stage2(gAh, ga0 + k0, ga1 + k0, sAh, wb);
    stage2(gAl, ga0 + k0, ga1 + k0, sAl, wb);
    stage2(gBh, gb0 + k0, gb1 + k0, sBh, wb);
    stage2(gBl, gb0 + k0, gb1 + k0, sBl, wb);
    __syncthreads();
    bf16x8 fah[4], fbh[4], fx[4];
#pragma unroll
    for (int t = 0; t < 4; ++t) {
      fah[t] = *(const bf16x8*)&sAh[(wm + t * 16 + lr) * 32 + q * 8];
      fbh[t] = *(const bf16x8*)&sBh[(wn + t * 16 + lr) * 32 + q * 8];
    }
#pragma unroll
    for (int mi = 0; mi < 4; ++mi)
#pragma unroll
      for (int ni = 0; ni < 4; ++ni)
        acc[mi][ni] = __builtin_amdgcn_mfma_f32_16x16x32_bf16(fah[mi], fbh[ni], acc[mi][ni], 0, 0, 0);
#pragma unroll
    for (int t = 0; t < 4; ++t)
      fx[t] = *(const bf16x8*)&sBl[(wn + t * 16 + lr) * 32 + q * 8];
#pragma unroll
    for (int mi = 0; mi < 4; ++mi)
#pragma unroll
      for (int ni = 0; ni < 4; ++ni)
        acc[mi][ni] = __builtin_amdgcn_mfma_f32_16x16x32_bf16(fah[mi], fx[ni], acc[mi][ni], 0, 0, 0);
#pragma unroll
    for (int t = 0; t < 4; ++t)
      fx[t] = *(const bf16x8*)&sAl[(wm + t * 16 + lr) * 32 + q * 8];
#pragma unroll
    for (int mi = 0; mi < 4; ++mi)
#pragma unroll
      for (int ni = 0; ni < 4; ++ni)
        acc[mi][ni] = __builtin_amdgcn_mfma_f32_16x16x32_bf16(fx[mi], fbh[ni], acc[mi][ni], 0, 0, 0);
  }
#pragma unroll
  for (int mi = 0; mi < 4; ++mi)
#pragma unroll
    for (int ni = 0; ni < 4; ++ni)
#pragma unroll
      for (int r = 0; r < 4; ++r)
        e[(size_t)(i0 + wm + mi * 16 + q * 4 + r) * L + (j0 + wn + ni * 16 + lr)] =
            acc[mi][ni][r];
}

// ---------------------------------------------------------------------------
// k_rowsoft: row max/sum over e; writes UNNORMALIZED exp to Pb bf16 and
// 1/rowsum to ROWINV (normalization deferred to k_pv epilogue).
// ---------------------------------------------------------------------------
__global__ __launch_bounds__(256) void k_rowsoft(float* __restrict__ ws) {
  float* slot = ws + (size_t)blockIdx.y * SLOT_F;
  const int row = blockIdx.x, tid = threadIdx.x;
  const float* er = slot + (size_t)row * L;
  float v[8]; float m = -INFINITY;
#pragma unroll
  for (int r = 0; r < 8; ++r) { v[r] = er[tid + r * 256]; m = fmaxf(m, v[r]); }
  __shared__ float red[4];
#pragma unroll
  for (int o = 32; o; o >>= 1) m = fmaxf(m, __shfl_xor(m, o));
  if ((tid & 63) == 0) red[tid >> 6] = m;
  __syncthreads();
  m = fmaxf(fmaxf(red[0], red[1]), fmaxf(red[2], red[3]));
  float ex[8], s = 0.f;
#pragma unroll
  for (int r = 0; r < 8; ++r) { ex[r] = __expf(v[r] - m); s += ex[r]; }
  __syncthreads();
#pragma unroll
  for (int o = 32; o; o >>= 1) s += __shfl_xor(s, o);
  if ((tid & 63) == 0) red[tid >> 6] = s;
  __syncthreads();
  unsigned short* P = (unsigned short*)(slot + PB_OFF) + (size_t)row * L;
#pragma unroll
  for (int r = 0; r < 8; ++r) P[tid + r * 256] = f2bf(ex[r]);
  if (tid == 0)
    slot[STAT + ROWINV + row] = 1.0f / (red[0] + red[1] + red[2] + red[3]);
}

// ---------------------------------------------------------------------------
// k_colmax: partial col-max over 256-row chunks of e (coalesced float4 rows).
// Grid (L/64 cols, L/256 rows, nb), 256 threads. Writes CMAXP[chunk][j].
// ---------------------------------------------------------------------------
__global__ __launch_bounds__(256) void k_colmax(float* __restrict__ ws) {
  float* slot = ws + (size_t)blockIdx.z * SLOT_F;
  const float* e = slot;
  float* st = slot + STAT;
  const int j0 = blockIdx.x * 64, i0 = blockIdx.y * 256;
  const int tid = threadIdx.x;
  const int rr = tid >> 4, c4 = (tid & 15) * 4;   // 16 row-groups x 16 col-quads
  float m0 = -INFINITY, m1 = -INFINITY, m2 = -INFINITY, m3 = -INFINITY;
#pragma unroll 4
  for (int i = rr; i < 256; i += 16) {
    float4 v = *(const float4*)(e + (size_t)(i0 + i) * L + j0 + c4);
    m0 = fmaxf(m0, v.x); m1 = fmaxf(m1, v.y);
    m2 = fmaxf(m2, v.z); m3 = fmaxf(m3, v.w);
  }
  __shared__ float red[16][64];
  red[rr][c4 + 0] = m0; red[rr][c4 + 1] = m1;
  red[rr][c4 + 2] = m2; red[rr][c4 + 3] = m3;
  __syncthreads();
  if (tid < 64) {
    float m = red[0][tid];
#pragma unroll
    for (int g = 1; g < 16; ++g) m = fmaxf(m, red[g][tid]);
    st[CMAXP + (size_t)blockIdx.y * L + j0 + tid] = m;
  }
}

// ---------------------------------------------------------------------------
// k_colexp: single read of e -> exp(v - colmax) -> transposed UNNORMALIZED
// bf16 PaT[j][i] + per-256-row-chunk partial col-sums (no atomics).
// Col-max finalized inline from the 8 CMAXP partials (k_colstat2 folded in).
// Grid (L/64 cols, L/256 rows, nb), 256 threads.
// ---------------------------------------------------------------------------
__global__ __launch_bounds__(256) void k_colexp(float* __restrict__ ws) {
  float* slot = ws + (size_t)blockIdx.z * SLOT_F;
  const float* e = slot;
  float* st = slot + STAT;
  const int j0 = blockIdx.x * 64, i0 = blockIdx.y * 256;
  const int tid = threadIdx.x;
  const int rr = tid >> 4, c4 = (tid & 15) * 4;
  __shared__ unsigned short sT[64][72];
  __shared__ float psumL[16][64];
  float cm[4], ps[4] = {0.f, 0.f, 0.f, 0.f};
#pragma unroll
  for (int k = 0; k < 4; ++k) {
    float m = st[CMAXP + j0 + c4 + k];
#pragma unroll
    for (int p = 1; p < 8; ++p)
      m = fmaxf(m, st[CMAXP + (size_t)p * L + j0 + c4 + k]);
    cm[k] = m;
  }
  unsigned short* PaT = (unsigned short*)(slot + PAT_OFF);
  for (int sub = 0; sub < 4; ++sub) {
    const int ib = i0 + sub * 64;
    __syncthreads();
#pragma unroll
    for (int p = 0; p < 4; ++p) {
      const int r = rr + p * 16;
      float4 v = *(const float4*)(e + (size_t)(ib + r) * L + j0 + c4);
      float e0 = __expf(v.x - cm[0]), e1 = __expf(v.y - cm[1]);
      float e2 = __expf(v.z - cm[2]), e3 = __expf(v.w - cm[3]);
      ps[0] += e0; ps[1] += e1; ps[2] += e2; ps[3] += e3;
      sT[c4 + 0][r] = f2bf(e0); sT[c4 + 1][r] = f2bf(e1);
      sT[c4 + 2][r] = f2bf(e2); sT[c4 + 3][r] = f2bf(e3);
    }
    __syncthreads();
    const int cc = tid >> 2, qd = tid & 3;
    uint4 o0 = *(const uint4*)&sT[cc][qd * 8];
    uint4 o1 = *(const uint4*)&sT[cc][32 + qd * 8];
    *(uint4*)&PaT[(size_t)(j0 + cc) * L + ib + qd * 8] = o0;
    *(uint4*)&PaT[(size_t)(j0 + cc) * L + ib + 32 + qd * 8] = o1;
  }
  psumL[rr][c4 + 0] = ps[0]; psumL[rr][c4 + 1] = ps[1];
  psumL[rr][c4 + 2] = ps[2]; psumL[rr][c4 + 3] = ps[3];
  __syncthreads();
  if (tid < 64) {
    float s = 0.f;
#pragma unroll
    for (int g = 0; g < 16; ++g) s += psumL[g][tid];
    st[CSUMP + (size_t)blockIdx.y * L + j0 + tid] = s;
  }
}

// ---------------------------------------------------------------------------
// k_pv (merged, double-buffered): out[m][d] = inv[m] * sum_k P[m][k]*W[d][k].
// pair = z>=nb selects {Pb, bt, out0, ROWINV} vs {PaT, at, out1, CSUMP}.
// BK=64; XOR-swizzled LDS (rule #21), bank-conflict-free (R5 PMC: 0).
// 2-phase pipeline: per K-step {preload all frags from buf[cur] (ds_read),
// issue next tile's 8 global_load_lds into buf[cur^1], 32 MFMA, ONE
// __syncthreads} — the barrier's vmcnt drain is the only serialization and
// the loads have the whole ds_read+MFMA phase in flight (T3-minimum recipe).
// Col-sum finalize (k_colfin) folded into the epilogue for pair=1.
// ---------------------------------------------------------------------------
__global__ __launch_bounds__(256) void k_pv(const unsigned short* __restrict__ at,
                                            const unsigned short* __restrict__ bt,
                                            float* __restrict__ ws,
                                            float* __restrict__ outB,
                                            int b0, int nb) {
  const int z = blockIdx.z;
  const int pair = (z >= nb) ? 1 : 0;
  const int bz = z - pair * nb;
  const int batch = b0 + bz;
  float* slot = ws + (size_t)bz * SLOT_F;
  const unsigned short* P =
      (const unsigned short*)(slot + (pair ? PAT_OFF : PB_OFF));
  const unsigned short* W = (pair ? at : bt) + (size_t)batch * D * L;
  float* out = outB + (size_t)(pair * BATCH + batch) * L * D;
  const float* st = slot + STAT;
  const int m0 = blockIdx.x * 128, d0 = blockIdx.y * 128;
  __shared__ unsigned short sP0[128 * 64], sP1[128 * 64];
  __shared__ unsigned short sW0[128 * 64], sW1[128 * 64];
  const int tid = threadIdx.x, lane = tid & 63, wave = tid >> 6;
  const int wm = (wave & 1) * 64, wn = (wave >> 1) * 64;
  const int q = lane >> 4, lr = lane & 15;
  // staging: lane's LDS slot (linear) = row*64 + (lane&7)*8 ushorts,
  // row = wave*8 + (lane>>3); source col pre-swizzled by XOR (row&7)*8.
  const int srow = wave * 8 + (lane >> 3);
  const int scolu = ((lane & 7) ^ (lane >> 3)) * 8;
  const size_t gp = (size_t)(m0 + srow) * L + scolu;
  const size_t gw = (size_t)(d0 + srow) * L + scolu;
  const int ldsb = wave * 512;
  const int swz = (lr & 7) << 3;
  f32x4 acc[4][4] = {};
  // prologue: stage K-tile 0 into buf0, drain (compiler emits vmcnt(0) at barrier)
#pragma unroll
  for (int it = 0; it < 4; ++it) {
    GLL16(P + gp + (size_t)it * 32 * L, sP0 + ldsb + it * 2048);
    GLL16(W + gw + (size_t)it * 32 * L, sW0 + ldsb + it * 2048);
  }
  __syncthreads();
  int cur = 0;
  for (int k0 = 0; k0 < L; k0 += 64) {
    unsigned short* bpP = cur ? sP1 : sP0;
    unsigned short* bpW = cur ? sW1 : sW0;
    unsigned short* bnP = cur ? sP0 : sP1;
    unsigned short* bnW = cur ? sW0 : sW1;
    // preload ALL fragments of the current K-tile (static indices)
    bf16x8 fa[2][4], fb[2][4];
#pragma unroll
    for (int kk = 0; kk < 2; ++kk)
#pragma unroll
      for (int t = 0; t < 4; ++t) {
        fa[kk][t] = *(const bf16x8*)&bpP[(wm + t * 16 + lr) * 64 + ((kk * 32 + q * 8) ^ swz)];
        fb[kk][t] = *(const bf16x8*)&bpW[(wn + t * 16 + lr) * 64 + ((kk * 32 + q * 8) ^ swz)];
      }
    // issue next tile's staging into the other buffer (flies during MFMA)
    if (k0 + 64 < L) {
#pragma unroll
      for (int it = 0; it < 4; ++it) {
        GLL16(P + gp + (size_t)it * 32 * L + k0 + 64, bnP + ldsb + it * 2048);
        GLL16(W + gw + (size_t)it * 32 * L + k0 + 64, bnW + ldsb + it * 2048);
      }
    }
#pragma unroll
    for (int kk = 0; kk < 2; ++kk)
#pragma unroll
      for (int mi = 0; mi < 4; ++mi)
#pragma unroll
        for (int ni = 0; ni < 4; ++ni)
          acc[mi][ni] = __builtin_amdgcn_mfma_f32_16x16x32_bf16(fa[kk][mi], fb[kk][ni], acc[mi][ni], 0, 0, 0);
    __syncthreads();   // drains next-tile vmcnt + all lgkm; buf reuse safe
    cur ^= 1;
  }
  float rsc[4][4];
#pragma unroll
  for (int mi = 0; mi < 4; ++mi)
#pragma unroll
    for (int r = 0; r < 4; ++r) {
      const int row = m0 + wm + mi * 16 + q * 4 + r;
      if (pair) {
        float s = 0.f;
#pragma unroll
        for (int k = 0; k < 8; ++k) s += st[CSUMP + (size_t)k * L + row];
        rsc[mi][r] = 1.0f / s;
      } else {
        rsc[mi][r] = st[ROWINV + row];
      }
    }
#pragma unroll
  for (int mi = 0; mi < 4; ++mi)
#pragma unroll
    for (int ni = 0; ni < 4; ++ni)
#pragma unroll
      for (int r = 0; r < 4; ++r)
        out[(size_t)(m0 + wm + mi * 16 + q * 4 + r) * D + (d0 + wn + ni * 16 + lr)] =
            acc[mi][ni][r] * rsc[mi][r];
}

extern "C" void kernel_launch(void* const* d_in, const int* in_sizes, int n_in,
                              void* d_out, int out_size, void* d_ws, size_t ws_size,
                              hipStream_t stream) {
  const float* a = (const float*)d_in[0];
  const float* b = (const float*)d_in[1];
  float* out = (float*)d_out;
  const size_t PL = (size_t)BATCH * D * L;
  unsigned short* at = (unsigned short*)d_ws;
  unsigned short* bt = at + PL;
  unsigned short* ah = bt + PL;
  unsigned short* al = ah + PL;
  unsigned short* bh = al + PL;
  unsigned short* bl = bh + PL;
  float* slots = (float*)(bl + PL);
  const size_t base_bytes = 6 * PL * sizeof(unsigned short);
  const size_t slot_bytes = (size_t)SLOT_F * sizeof(float);
  int S = 1;
  if (ws_size > base_bytes + slot_bytes)
    S = (int)((ws_size - base_bytes) / slot_bytes);
  if (S > BATCH) S = BATCH;
  if (S < 1) S = 1;

  hipLaunchKernelGGL(k_prep, dim3(L / 64, D / 64, 2 * BATCH), dim3(256), 0, stream,
                     a, b, at, bt, ah, al, bh, bl);
  for (int b0 = 0; b0 < BATCH; b0 += S) {
    int nb = (BATCH - b0 < S) ? (BATCH - b0) : S;
    hipLaunchKernelGGL(k_gemm_e, dim3(16, 16, nb), dim3(256), 0, stream,
                       ah, al, bh, bl, slots, b0);
    hipLaunchKernelGGL(k_rowsoft, dim3(L, nb), dim3(256), 0, stream, slots);
    hipLaunchKernelGGL(k_colmax, dim3(L / 64, L / 256, nb), dim3(256), 0, stream, slots);
    hipLaunchKernelGGL(k_colexp, dim3(L / 64, L / 256, nb), dim3(256), 0, stream, slots);
    hipLaunchKernelGGL(k_pv, dim3(16, 8, 2 * nb), dim3(256), 0, stream,
                       at, bt, slots, out, b0, nb);
  }
}